// Round 4
// baseline (27361.761 us; speedup 1.0000x reference)
//
#include <hip/hip_runtime.h>

// Problem constants
#define B_    32
#define T_    2048
#define F_    64
#define H_    256
#define OUT_  64
#define G3_   768           // 3*H
#define NWRK  16            // worker WGs (all on ONE elected XCD)
#define NLNCH 128           // launched WGs (election pool; pigeonhole -> some XCD holds >=16)
#define WGT   512           // threads per WG (8 waves)

// Dual rings, 4 slots x 16 roles x 1024 u32 (4 KB/block).
// Word = {tag16<<16 | f16}. tag16 = (iter&15)<<12 | tick  (tick <= 2049 < 4096).
// Block: words [0..511] = h1[bb*16+jl], [512..1023] = h2[...].
// ringF: plain stores / plain loads + buffer_inv  (same-XCD L2 transport).
// ringS: sc1 stores / sc1 loads (agent scope, R1-verified fallback protocol).
#define D_        4
#define BLK_W     1024
#define RING_U32  (D_ * 16 * BLK_W)
#define XN_BYTES  (B_ * T_ * F_ * 2)             // 8 MB fp16 LN(x), [T][B][F]
#define RINGF_OFF XN_BYTES
#define RINGS_OFF (RINGF_OFF + RING_U32 * 4)
#define CTRL_OFF  (RINGS_OFF + RING_U32 * 4)     // int cnt[8], chosen @8, iter @12
#define FASTTRY   4096                           // fast-poll budget before sticky fallback

typedef _Float16 half8 __attribute__((ext_vector_type(8)));
typedef _Float16 half4 __attribute__((ext_vector_type(4)));
typedef float    f32x4 __attribute__((ext_vector_type(4)));
typedef unsigned int u32x4 __attribute__((ext_vector_type(4)));
typedef unsigned long long u64;

#define LD_A(p)     __hip_atomic_load((p),  __ATOMIC_RELAXED, __HIP_MEMORY_SCOPE_AGENT)
#define ST_A(p, v)  __hip_atomic_store((p), (v), __ATOMIC_RELAXED, __HIP_MEMORY_SCOPE_AGENT)
#define ST_W(p, v)  __hip_atomic_store((p), (v), __ATOMIC_RELAXED, __HIP_MEMORY_SCOPE_WORKGROUP)

__device__ __forceinline__ float sigf(float x) {
    x = fminf(fmaxf(x, -30.f), 30.f);
    return 1.f / (1.f + __expf(-x));
}
__device__ __forceinline__ float tanhfast(float x) {
    x = fminf(fmaxf(x, -15.f), 15.f);
    float e = __expf(2.f * x);
    return (e - 1.f) / (e + 1.f);
}
__device__ __forceinline__ unsigned short f16b(float f) {
    union { _Float16 h; unsigned short u; } c; c.h = (_Float16)f; return c.u;
}
// pack low16 of 4 words into u64 (4 consecutive fp16)
__device__ __forceinline__ u64 pack4(u32x4 v) {
    return (u64)(v.x & 0xFFFFu) | ((u64)(v.y & 0xFFFFu) << 16)
         | ((u64)(v.z & 0xFFFFu) << 32) | ((u64)v.w << 48);
}
__device__ __forceinline__ bool ok4(u32x4 q, unsigned tg) {
    return (q.x >> 16) == tg && (q.y >> 16) == tg && (q.z >> 16) == tg && (q.w >> 16) == tg;
}

// ---------------------------------------------------------------------------
// Init: zero both rings, reset election ctrl, bump launch-iteration counter,
// out = bias broadcast.
// ---------------------------------------------------------------------------
__global__ void init_kernel(float* __restrict__ out, const float* __restrict__ bd,
                            unsigned int* __restrict__ rings, int* __restrict__ ctrl) {
    int t = blockIdx.x * 256 + threadIdx.x;              // 4096 threads
    if (t < B_ * OUT_) out[t] = bd[t & (OUT_ - 1)];
    if (t < 12)       ctrl[t] = (t == 8) ? -1 : 0;
    else if (t == 12) ctrl[12] = ctrl[12] + 1;           // persistent iter counter
    for (int p = t; p < 2 * RING_U32; p += 4096) rings[p] = 0u;  // ringF | ringS
}

// ---------------------------------------------------------------------------
// LayerNorm over F=64, fp16 output TRANSPOSED to [T][B][F]. (unchanged)
// ---------------------------------------------------------------------------
__global__ __launch_bounds__(256) void ln_kernel(const float* __restrict__ x,
                                                 const float* __restrict__ gamma,
                                                 const float* __restrict__ beta,
                                                 _Float16* __restrict__ xn) {
    const int tid = threadIdx.x;
    const int r = tid >> 4, q = tid & 15;
    const size_t row = (size_t)blockIdx.x * 16 + r;      // = b*T + t
    const int b = (int)(row >> 11);
    const int t = (int)(row & 2047);
    const float4 v  = *(const float4*)(x + row * F_ + q * 4);
    const float4 g  = *(const float4*)(gamma + q * 4);
    const float4 be = *(const float4*)(beta + q * 4);
    float s = v.x + v.y + v.z + v.w;
    s += __shfl_xor(s, 1, 16); s += __shfl_xor(s, 2, 16);
    s += __shfl_xor(s, 4, 16); s += __shfl_xor(s, 8, 16);
    const float mu = s * (1.f / 64.f);
    const float dx = v.x - mu, dy = v.y - mu, dz = v.z - mu, dw = v.w - mu;
    float qq = dx * dx + dy * dy + dz * dz + dw * dw;
    qq += __shfl_xor(qq, 1, 16); qq += __shfl_xor(qq, 2, 16);
    qq += __shfl_xor(qq, 4, 16); qq += __shfl_xor(qq, 8, 16);
    const float rs = rsqrtf(qq * (1.f / 64.f) + 1e-3f);
    half4 o;
    o[0] = (_Float16)(dx * rs * g.x + be.x);
    o[1] = (_Float16)(dy * rs * g.y + be.y);
    o[2] = (_Float16)(dz * rs * g.z + be.z);
    o[3] = (_Float16)(dw * rs * g.w + be.w);
    *(half4*)(xn + ((size_t)t * B_ + b) * F_ + q * 4) = o;
}

// ---------------------------------------------------------------------------
// Fused dual-layer persistent GRU on ONE elected XCD.
//
// Fast transport: producers plain-store (write-through L1 -> shared XCD L2);
// consumers poll with { buffer_inv ; plain loads ; tag check }. buffer_inv
// invalidates the CU's vector L1 (the only stale layer within an XCD), so
// loads are served by the coherent local L2 (~200cy) instead of the fabric
// round-trip (~1000+cy) that sc1 loads take.
// Fallback: producers ALSO sc1-publish to ringS; any thread whose fast poll
// exceeds FASTTRY tries switches permanently to sc1 polling of ringS (the
// R1-verified agent protocol). Kernel cannot hang on a wrong fast-path
// theory -- it degrades to ~R1 speed.
// Tags carry (iter&15)<<12 so a previous launch's ring contents (same
// addresses, same tick numbers) can never false-match.
// ---------------------------------------------------------------------------
__global__ __launch_bounds__(WGT) void gru_fused(
    const _Float16* __restrict__ xn,
    const float* __restrict__ k1, const float* __restrict__ rk1,
    const float* __restrict__ b1, const float* __restrict__ k2,
    const float* __restrict__ rk2, const float* __restrict__ b2,
    const float* __restrict__ wd, float* __restrict__ out,
    unsigned int* __restrict__ ringF, unsigned int* __restrict__ ringS,
    int* __restrict__ ctrl) {
    const int tid  = threadIdx.x;
    const int lane = tid & 63;
    const int wave = tid >> 6;           // 8 waves
    const int mt   = wave & 1;
    const int nt   = wave >> 1;          // 0..3
    const int ln   = lane & 15;
    const int quad = lane >> 4;

    __shared__ _Float16 h1s[32][264];
    __shared__ _Float16 h2s[32][264];
    __shared__ float Cs[4][32][52];      // c0,c1 (L1) + c2,c3 (L2)
    __shared__ float hs[32][16];
    __shared__ int s_role;

    const unsigned tagbase = (((unsigned)ctrl[12]) & 15u) << 12;

    // ---------------- election ----------------
    if (tid == 0) {
        unsigned xcd;
        asm volatile("s_getreg_b32 %0, hwreg(HW_REG_XCC_ID)" : "=s"(xcd));
        xcd &= 7u;
        const int r = __hip_atomic_fetch_add(&ctrl[xcd], 1, __ATOMIC_RELAXED,
                                             __HIP_MEMORY_SCOPE_AGENT);
        if (r == NWRK - 1) {             // 16th WG on my XCD: latch it
            int expct = -1;
            __hip_atomic_compare_exchange_strong(&ctrl[8], &expct, (int)xcd,
                __ATOMIC_RELAXED, __ATOMIC_RELAXED, __HIP_MEMORY_SCOPE_AGENT);
        }
        int c;
        while ((c = LD_A(&ctrl[8])) < 0) __builtin_amdgcn_s_sleep(8);
        s_role = (c == (int)xcd && r < NWRK) ? r : -1;
    }
    __syncthreads();
    const int w = s_role;                // uniform per WG
    if (w < 0) return;                   // non-elected WGs exit

    // zero LDS h state (tick 0 consumes zeros)
    for (int p = tid; p < 32 * 264; p += WGT) {
        ((_Float16*)h1s)[p] = (_Float16)0.f;
        ((_Float16*)h2s)[p] = (_Float16)0.f;
    }
    __syncthreads();

    const int  lc    = nt * 16 + ln;
    const bool valid = (lc < 48);        // nt<3 (wave-uniform)
    const int  gate  = lc >> 4;
    const int  hidx  = lc & 15;
    const int  jl    = tid & 15;
    const int  bb    = tid >> 4;         // 0..31
    const int  m     = mt * 16 + ln;     // batch row for A fragments

    // ---------------- weights (both layers, 16 hidden units) ----------------
    const int gcol = valid ? (gate * H_ + w * 16 + hidx) : 0;
    half8 fk1[2], frk1[8], fk2[8], frk2[8];
#pragma unroll
    for (int ks = 0; ks < 2; ++ks) {
        half8 f;
#pragma unroll
        for (int j = 0; j < 8; ++j) {
            const float v = k1[(ks * 32 + quad * 8 + j) * G3_ + gcol];
            f[j] = valid ? (_Float16)v : (_Float16)0.f;
        }
        fk1[ks] = f;
    }
#pragma unroll
    for (int ks = 0; ks < 8; ++ks) {
        half8 fa, fb, fc;
#pragma unroll
        for (int j = 0; j < 8; ++j) {
            const int k = ks * 32 + quad * 8 + j;
            const float va = rk1[k * G3_ + gcol];
            const float vb = k2 [k * G3_ + gcol];
            const float vc = rk2[k * G3_ + gcol];
            fa[j] = valid ? (_Float16)va : (_Float16)0.f;
            fb[j] = valid ? (_Float16)vb : (_Float16)0.f;
            fc[j] = valid ? (_Float16)vc : (_Float16)0.f;
        }
        frk1[ks] = fa; fk2[ks] = fb; frk2[ks] = fc;
    }
    const int gc = w * 16 + jl;
    const float bxz1 = b1[gc],       bxr1 = b1[H_ + gc],       bxh1 = b1[2 * H_ + gc];
    const float bhz1 = b1[G3_ + gc], bhr1 = b1[G3_ + H_ + gc], bhh1 = b1[G3_ + 2 * H_ + gc];
    const float bxz2 = b2[gc],       bxr2 = b2[H_ + gc],       bxh2 = b2[2 * H_ + gc];
    const float bhz2 = b2[G3_ + gc], bhr2 = b2[G3_ + H_ + gc], bhh2 = b2[G3_ + 2 * H_ + gc];
    float h1m = 0.f, h2m = 0.f;

    // staging map: 32 threads per source role; thread covers 8 dwordx4
    // (byte offsets k*512) of the source's 4 KB block.
    const int w2  = tid >> 5;            // source role 0..15
    const int t32 = tid & 31;
    const int brs = t32 >> 2;            // base batch row within octet
    const int c0f = w2 * 16 + (t32 & 3) * 4;
    bool slow = false;                   // sticky per-thread transport mode

    for (int j = 0; j <= T_; ++j) {
        // L1 x-projection (independent of handoff) first
        f32x4 c0 = {0.f, 0.f, 0.f, 0.f};
        if (j < T_ && nt < 3) {
            const _Float16* xr = xn + ((size_t)j * B_ + m) * F_ + quad * 8;
            const half8 ax0 = *(const half8*)(xr);
            const half8 ax1 = *(const half8*)(xr + 32);
            c0 = __builtin_amdgcn_mfma_f32_16x16x32_f16(ax0, fk1[0], c0, 0, 0, 0);
            c0 = __builtin_amdgcn_mfma_f32_16x16x32_f16(ax1, fk1[1], c0, 0, 0, 0);
        }
        // poll peers' combined blocks (tag tagbase|j), stage to LDS
        if (j >= 1) {
            const unsigned tg   = tagbase | (unsigned)j;
            const unsigned bofs = (((unsigned)(j - 1) & 3u) * 16 + (unsigned)w2) * BLK_W + (t32 << 2);
            const unsigned* srcF = ringF + bofs;
            const unsigned* srcS = ringS + bofs;
            u32x4 q0, q1, q2, q3, q4, q5, q6, q7;
            bool got = false;
            if (!slow) {
                int tries = 0;
                for (;;) {
                    asm volatile(
                        "buffer_inv\n\t"
                        "s_waitcnt vmcnt(0)\n\t"
                        "global_load_dwordx4 %0, %8, off\n\t"
                        "global_load_dwordx4 %1, %8, off offset:512\n\t"
                        "global_load_dwordx4 %2, %8, off offset:1024\n\t"
                        "global_load_dwordx4 %3, %8, off offset:1536\n\t"
                        "global_load_dwordx4 %4, %8, off offset:2048\n\t"
                        "global_load_dwordx4 %5, %8, off offset:2560\n\t"
                        "global_load_dwordx4 %6, %8, off offset:3072\n\t"
                        "global_load_dwordx4 %7, %8, off offset:3584\n\t"
                        "s_waitcnt vmcnt(0)"
                        : "=&v"(q0), "=&v"(q1), "=&v"(q2), "=&v"(q3),
                          "=&v"(q4), "=&v"(q5), "=&v"(q6), "=&v"(q7)
                        : "v"(srcF) : "memory");
                    if (ok4(q0, tg) && ok4(q1, tg) && ok4(q2, tg) && ok4(q3, tg) &&
                        ok4(q4, tg) && ok4(q5, tg) && ok4(q6, tg) && ok4(q7, tg)) {
                        got = true; break;
                    }
                    if (++tries > FASTTRY) { slow = true; break; }  // sticky fallback
                    __builtin_amdgcn_s_sleep(1);
                }
            }
            if (!got) {                  // agent-scope fallback (R1 protocol)
                for (;;) {
                    asm volatile(
                        "global_load_dwordx4 %0, %8, off sc1\n\t"
                        "global_load_dwordx4 %1, %8, off offset:512 sc1\n\t"
                        "global_load_dwordx4 %2, %8, off offset:1024 sc1\n\t"
                        "global_load_dwordx4 %3, %8, off offset:1536 sc1\n\t"
                        "global_load_dwordx4 %4, %8, off offset:2048 sc1\n\t"
                        "global_load_dwordx4 %5, %8, off offset:2560 sc1\n\t"
                        "global_load_dwordx4 %6, %8, off offset:3072 sc1\n\t"
                        "global_load_dwordx4 %7, %8, off offset:3584 sc1\n\t"
                        "s_waitcnt vmcnt(0)"
                        : "=&v"(q0), "=&v"(q1), "=&v"(q2), "=&v"(q3),
                          "=&v"(q4), "=&v"(q5), "=&v"(q6), "=&v"(q7)
                        : "v"(srcS) : "memory");
                    if (ok4(q0, tg) && ok4(q1, tg) && ok4(q2, tg) && ok4(q3, tg) &&
                        ok4(q4, tg) && ok4(q5, tg) && ok4(q6, tg) && ok4(q7, tg)) break;
                    __builtin_amdgcn_s_sleep(1);
                }
            }
            *(u64*)(&h1s[brs     ][c0f]) = pack4(q0);
            *(u64*)(&h1s[brs +  8][c0f]) = pack4(q1);
            *(u64*)(&h1s[brs + 16][c0f]) = pack4(q2);
            *(u64*)(&h1s[brs + 24][c0f]) = pack4(q3);
            *(u64*)(&h2s[brs     ][c0f]) = pack4(q4);
            *(u64*)(&h2s[brs +  8][c0f]) = pack4(q5);
            *(u64*)(&h2s[brs + 16][c0f]) = pack4(q6);
            *(u64*)(&h2s[brs + 24][c0f]) = pack4(q7);
        }
        __syncthreads();                 // barrier A: staging done

        f32x4 c1 = {0.f, 0.f, 0.f, 0.f};
        f32x4 c2 = c1, c3 = c1;
        if (nt < 3) {
            if (j < T_) {
#pragma unroll
                for (int ks = 0; ks < 8; ++ks) {
                    const half8 a1 = *(const half8*)(&h1s[m][ks * 32 + quad * 8]);
                    c1 = __builtin_amdgcn_mfma_f32_16x16x32_f16(a1, frk1[ks], c1, 0, 0, 0);
                }
            }
            if (j >= 1) {
#pragma unroll
                for (int ks = 0; ks < 8; ++ks) {
                    const half8 a1 = *(const half8*)(&h1s[m][ks * 32 + quad * 8]);
                    const half8 a2 = *(const half8*)(&h2s[m][ks * 32 + quad * 8]);
                    c2 = __builtin_amdgcn_mfma_f32_16x16x32_f16(a1, fk2[ks],  c2, 0, 0, 0);
                    c3 = __builtin_amdgcn_mfma_f32_16x16x32_f16(a2, frk2[ks], c3, 0, 0, 0);
                }
            }
            if (valid) {
                const int r0 = mt * 16 + quad * 4;
#pragma unroll
                for (int rr = 0; rr < 4; ++rr) {
                    Cs[0][r0 + rr][lc] = c0[rr];
                    Cs[1][r0 + rr][lc] = c1[rr];
                    Cs[2][r0 + rr][lc] = c2[rr];
                    Cs[3][r0 + rr][lc] = c3[rr];
                }
            }
        }
        __syncthreads();                 // barrier B: Cs ready

        // gates (both layers) + dual tagged publish
        if (j < T_) {
            const float xz = Cs[0][bb][jl]      + bxz1;
            const float xr = Cs[0][bb][16 + jl] + bxr1;
            const float xh = Cs[0][bb][32 + jl] + bxh1;
            const float rz = Cs[1][bb][jl]      + bhz1;
            const float rr = Cs[1][bb][16 + jl] + bhr1;
            const float rh = Cs[1][bb][32 + jl] + bhh1;
            const float z  = sigf(xz + rz);
            const float r  = sigf(xr + rr);
            const float hh = tanhfast(xh + r * rh);
            h1m = z * h1m + (1.f - z) * hh;
        }
        if (j >= 1) {
            const float xz = Cs[2][bb][jl]      + bxz2;
            const float xr = Cs[2][bb][16 + jl] + bxr2;
            const float xh = Cs[2][bb][32 + jl] + bxh2;
            const float rz = Cs[3][bb][jl]      + bhz2;
            const float rr = Cs[3][bb][16 + jl] + bhr2;
            const float rh = Cs[3][bb][32 + jl] + bhh2;
            const float z  = sigf(xz + rz);
            const float r  = sigf(xr + rr);
            const float hh = tanhfast(xh + r * rh);
            h2m = z * h2m + (1.f - z) * hh;
        }
        if (j < T_) {                    // publish {h1[j], h2[j-1]} tag tagbase|(j+1)
            const unsigned off = (((unsigned)j & 3u) * 16 + (unsigned)w) * BLK_W + (bb << 4) + jl;
            const unsigned th  = (tagbase | (unsigned)(j + 1)) << 16;
            const unsigned v1  = th | (unsigned)f16b(h1m);
            const unsigned v2  = th | (unsigned)f16b(h2m);
            ST_W(ringF + off,       v1);         // fast copy: plain store -> local L2
            ST_W(ringF + off + 512, v2);
            ST_A(ringS + off,       v1);         // insurance copy: agent scope
            ST_A(ringS + off + 512, v2);
        }
    }

    // ---- final dense: out[b][o] += sum_j h2[b][16w+j] * wd[16w+j][o]
    hs[bb][jl] = h2m;                    // h2m = h2[T-1]
    __syncthreads();
    const int o  = tid & 63;
    const int bq = tid >> 6;             // 0..7
    for (int pass = 0; pass < 4; ++pass) {
        const int b = pass * 8 + bq;
        float acc = 0.f;
#pragma unroll
        for (int jj = 0; jj < 16; ++jj) acc += hs[b][jj] * wd[(w * 16 + jj) * OUT_ + o];
        atomicAdd(&out[b * OUT_ + o], acc);
    }
}

// ---------------------------------------------------------------------------
extern "C" void kernel_launch(void* const* d_in, const int* in_sizes, int n_in,
                              void* d_out, int out_size, void* d_ws, size_t ws_size,
                              hipStream_t stream) {
    const float* x     = (const float*)d_in[0];
    const float* gamma = (const float*)d_in[1];
    const float* beta  = (const float*)d_in[2];
    const float* k1    = (const float*)d_in[3];
    const float* rk1   = (const float*)d_in[4];
    const float* b1    = (const float*)d_in[5];
    const float* k2    = (const float*)d_in[6];
    const float* rk2   = (const float*)d_in[7];
    const float* b2    = (const float*)d_in[8];
    const float* wd    = (const float*)d_in[9];
    const float* bd    = (const float*)d_in[10];
    float* out = (float*)d_out;

    char* ws = (char*)d_ws;
    _Float16*     xn    = (_Float16*)ws;
    unsigned int* ringF = (unsigned int*)(ws + RINGF_OFF);
    unsigned int* ringS = (unsigned int*)(ws + RINGS_OFF);
    int*          ctrl  = (int*)(ws + CTRL_OFF);

    hipLaunchKernelGGL(init_kernel, dim3(16), dim3(256), 0, stream, out, bd, ringF, ctrl);
    hipLaunchKernelGGL(ln_kernel, dim3(B_ * T_ / 16), dim3(256), 0, stream, x, gamma, beta, xn);

    void* args[] = {(void*)&xn, (void*)&k1, (void*)&rk1, (void*)&b1, (void*)&k2,
                    (void*)&rk2, (void*)&b2, (void*)&wd, (void*)&out,
                    (void*)&ringF, (void*)&ringS, (void*)&ctrl};
    hipLaunchCooperativeKernel((void*)gru_fused, dim3(NLNCH), dim3(WGT), args, 0, stream);
}

// Round 7
// 6071.227 us; speedup vs baseline: 4.5068x; 4.5068x over previous
//
#include <hip/hip_runtime.h>

// Problem constants
#define B_    32
#define T_    2048
#define F_    64
#define H_    256
#define OUT_  64
#define G3_   768           // 3*H
#define NWG1  16            // layer-1 pipeline WGs
#define NWG2  16            // layer-2 pipeline WGs
#define TOTAL_WG (NWG1 + NWG2)
#define WGT   512           // threads per WG (8 waves)

// Source-major packs: fp16 [par][w(16)][bb(32)][16 cols]; 1 KB contiguous per
// (par, w). h1 depth 4 (64 KB), h2 depth 2 (32 KB).
// Flags are REPLICATED PER CONSUMER: flags[src 0..31][cons 0..31] (64B lines),
// prog[src 0..15][cons 0..15] -- each consumer polls a private line, removing
// the 512-1024-thread sharing storm per line of the R0 layout. Values and
// ordering are identical to the verified protocol (drain -> barrier -> flag).
#define PBLK   512                               // halfs per (par,w) block
#define XN_BYTES (B_ * T_ * F_ * 2)              // 8,388,608 fp16 LN(x), [T][B][F]
#define S1_OFF   XN_BYTES                        // p1: 64 KB
#define S2_OFF   (S1_OFF + 4 * 16 * PBLK * 2)    // p2: 32 KB
#define FLAG_OFF (S2_OFF + 2 * 16 * PBLK * 2)    // flags: 32x32 lines = 64 KB
#define PROG_OFF (FLAG_OFF + 32 * 32 * 64)       // prog: 16x16 lines = 16 KB

typedef _Float16 half8 __attribute__((ext_vector_type(8)));
typedef _Float16 half4 __attribute__((ext_vector_type(4)));
typedef float    f32x4 __attribute__((ext_vector_type(4)));
typedef unsigned long long u64;

#define LD_A(p)    __hip_atomic_load((p),  __ATOMIC_RELAXED, __HIP_MEMORY_SCOPE_AGENT)
#define ST_A(p, v) __hip_atomic_store((p), (v), __ATOMIC_RELAXED, __HIP_MEMORY_SCOPE_AGENT)

__device__ __forceinline__ float sigf(float x) {
    x = fminf(fmaxf(x, -30.f), 30.f);
    return 1.f / (1.f + __expf(-x));
}
__device__ __forceinline__ float tanhfast(float x) {
    x = fminf(fmaxf(x, -15.f), 15.f);
    float e = __expf(2.f * x);
    return (e - 1.f) / (e + 1.f);
}
__device__ __forceinline__ unsigned short f16b(float f) {
    union { _Float16 h; unsigned short u; } c; c.h = (_Float16)f; return c.u;
}
// Gather 4 neighboring lanes' fp16 (jl, jl^1, jl^2, jl^3) into one u64 (LE by jl)
__device__ __forceinline__ u64 gather4(unsigned short u, int jl) {
    unsigned int p = (unsigned int)__shfl_xor((int)(unsigned int)u, 1);
    unsigned int lo32 = (jl & 1) ? ((p & 0xffffu) | ((unsigned int)u << 16))
                                 : ((unsigned int)u | (p << 16));
    unsigned int q = (unsigned int)__shfl_xor((int)lo32, 2);
    return (jl & 2) ? (((u64)lo32 << 32) | q)
                    : ((u64)lo32 | ((u64)q << 32));
}

// ---------------------------------------------------------------------------
// Init: zero packs + replicated flags/prog, out = bias broadcast
// ---------------------------------------------------------------------------
__global__ void init_kernel(float* __restrict__ out, const float* __restrict__ bd,
                            _Float16* __restrict__ packs, unsigned int* __restrict__ flg) {
    int t = blockIdx.x * 256 + threadIdx.x;              // 4096 threads
    if (t < B_ * OUT_) out[t] = bd[t & (OUT_ - 1)];
    for (int p = t; p < 20480; p += 4096) flg[p] = 0u;   // flags(16K dw) + prog(4K dw)
    for (int p = t; p < 6 * 16 * PBLK; p += 4096) packs[p] = (_Float16)0.f;
}

// ---------------------------------------------------------------------------
// LayerNorm over F=64, fp16 output TRANSPOSED to [T][B][F]. (verified)
// ---------------------------------------------------------------------------
__global__ __launch_bounds__(256) void ln_kernel(const float* __restrict__ x,
                                                 const float* __restrict__ gamma,
                                                 const float* __restrict__ beta,
                                                 _Float16* __restrict__ xn) {
    const int tid = threadIdx.x;
    const int r = tid >> 4, q = tid & 15;
    const size_t row = (size_t)blockIdx.x * 16 + r;      // = b*T + t
    const int b = (int)(row >> 11);
    const int t = (int)(row & 2047);
    const float4 v  = *(const float4*)(x + row * F_ + q * 4);
    const float4 g  = *(const float4*)(gamma + q * 4);
    const float4 be = *(const float4*)(beta + q * 4);
    float s = v.x + v.y + v.z + v.w;
    s += __shfl_xor(s, 1, 16); s += __shfl_xor(s, 2, 16);
    s += __shfl_xor(s, 4, 16); s += __shfl_xor(s, 8, 16);
    const float mu = s * (1.f / 64.f);
    const float dx = v.x - mu, dy = v.y - mu, dz = v.z - mu, dw = v.w - mu;
    float qq = dx * dx + dy * dy + dz * dz + dw * dw;
    qq += __shfl_xor(qq, 1, 16); qq += __shfl_xor(qq, 2, 16);
    qq += __shfl_xor(qq, 4, 16); qq += __shfl_xor(qq, 8, 16);
    const float rs = rsqrtf(qq * (1.f / 64.f) + 1e-3f);
    half4 o;
    o[0] = (_Float16)(dx * rs * g.x + be.x);
    o[1] = (_Float16)(dy * rs * g.y + be.y);
    o[2] = (_Float16)(dz * rs * g.z + be.z);
    o[3] = (_Float16)(dw * rs * g.w + be.w);
    *(half4*)(xn + ((size_t)t * B_ + b) * F_ + q * 4) = o;
}

// ---------------------------------------------------------------------------
// Dual-pipeline persistent GRU (verified structure), per-consumer flags.
// WGs 0..15  (L1): h1 chain. WGs 16..31 (L2): h2 chain (lag 1).
// Protocol identical to the verified kernel: drain -> sync -> flag store;
// narrow per-source polls. Only change: flag/prog lines replicated per
// consumer (src writes 32/16 copies with one wave store; each consumer
// group polls a private line).
// ---------------------------------------------------------------------------
__global__ __launch_bounds__(WGT) void gru_main(
    const _Float16* __restrict__ xn,
    const float* __restrict__ k1, const float* __restrict__ rk1,
    const float* __restrict__ b1, const float* __restrict__ k2,
    const float* __restrict__ rk2, const float* __restrict__ b2,
    const float* __restrict__ wd, float* __restrict__ out,
    _Float16* __restrict__ p1, _Float16* __restrict__ p2,
    unsigned int* __restrict__ flags, unsigned int* __restrict__ prog) {
    const int tid  = threadIdx.x;
    const int lane = tid & 63;
    const int wave = tid >> 6;           // 8 waves
    const int mt   = wave & 1;
    const int nt   = wave >> 1;          // 0..3
    const int ln   = lane & 15;
    const int quad = lane >> 4;

    __shared__ _Float16 h1s[32][264];    // 528B rows
    __shared__ _Float16 h2s[32][264];
    __shared__ float Cs[2][32][52];
    __shared__ float hs[32][16];

    const int  lc    = nt * 16 + ln;
    const bool valid = (lc < 48);
    const int  gate  = lc >> 4;
    const int  hidx  = lc & 15;
    const int  jl    = tid & 15;
    const int  bb    = tid >> 4;         // 0..31
    const int  m     = mt * 16 + ln;     // batch row for A fragments

    if (blockIdx.x < NWG1) {
        // ================= L1 pipeline =================
        const int w    = blockIdx.x;
        const int gcol = valid ? (gate * H_ + w * 16 + hidx) : 0;
        half8 fk1[2], frk1[8];
#pragma unroll
        for (int ks = 0; ks < 2; ++ks) {
            half8 f;
#pragma unroll
            for (int j = 0; j < 8; ++j) {
                const float v = k1[(ks * 32 + quad * 8 + j) * G3_ + gcol];
                f[j] = valid ? (_Float16)v : (_Float16)0.f;
            }
            fk1[ks] = f;
        }
#pragma unroll
        for (int ks = 0; ks < 8; ++ks) {
            half8 f;
#pragma unroll
            for (int j = 0; j < 8; ++j) {
                const float v = rk1[(ks * 32 + quad * 8 + j) * G3_ + gcol];
                f[j] = valid ? (_Float16)v : (_Float16)0.f;
            }
            frk1[ks] = f;
        }
        const int gc = w * 16 + jl;
        const float bxz = b1[gc],       bxr = b1[H_ + gc],       bxh = b1[2 * H_ + gc];
        const float bhz = b1[G3_ + gc], bhr = b1[G3_ + H_ + gc], bhh = b1[G3_ + 2 * H_ + gc];
        float h1m = 0.f;

        // staging map: 32 threads per source WG, contiguous 1 KB block.
        // PRIVATE poll lines: flags[src w2][cons w], prog[src w2][cons w].
        const int w2  = tid >> 5;                  // source WG 0..15
        const int t32 = tid & 31;
        const unsigned* f1p = flags + (w2 * 32 + w) * 16;
        const unsigned* f2p = prog  + (w2 * 16 + w) * 16;

        for (int i = 0; i < T_; ++i) {
            // xproj (no cross-WG dep) before polling
            f32x4 c0 = {0.f, 0.f, 0.f, 0.f};
            {
                half8 ax0 = *(const half8*)(xn + ((size_t)i * B_ + m) * F_ + quad * 8);
                half8 ax1 = *(const half8*)(xn + ((size_t)i * B_ + m) * F_ + 32 + quad * 8);
                c0 = __builtin_amdgcn_mfma_f32_16x16x32_f16(ax0, fk1[0], c0, 0, 0, 0);
                c0 = __builtin_amdgcn_mfma_f32_16x16x32_f16(ax1, fk1[1], c0, 0, 0, 0);
            }
            // poll own source flag + back-pressure, then coalesced 1 KB stage
            {
                const unsigned tgt1 = (unsigned)i;
                const unsigned tgt2 = (i >= 4) ? (unsigned)(i - 3) : 0u;
                while (LD_A(f1p) < tgt1 || LD_A(f2p) < tgt2)
                    __builtin_amdgcn_s_sleep(1);
                // block base: parity (i-1)&3 == (i+3)&3, source w2
                const u64* src = (const u64*)(p1 + (((unsigned)(i + 3) & 3u) * 16 + w2) * PBLK);
                u64 q0 = LD_A(src + t32);
                u64 q1 = LD_A(src + 32 + t32);
                u64 q2 = LD_A(src + 64 + t32);
                u64 q3 = LD_A(src + 96 + t32);
                const int b0 = t32 >> 2;           // bb for k=0
                const int c0f = w2 * 16 + (t32 & 3) * 4;
                *(u64*)(&h1s[b0][c0f])      = q0;
                *(u64*)(&h1s[b0 + 8][c0f])  = q1;
                *(u64*)(&h1s[b0 + 16][c0f]) = q2;
                *(u64*)(&h1s[b0 + 24][c0f]) = q3;
            }
            __syncthreads();

            f32x4 c1 = {0.f, 0.f, 0.f, 0.f};
#pragma unroll
            for (int ks = 0; ks < 8; ++ks) {
                half8 a1 = *(const half8*)(&h1s[m][ks * 32 + quad * 8]);
                c1 = __builtin_amdgcn_mfma_f32_16x16x32_f16(a1, frk1[ks], c1, 0, 0, 0);
            }
            if (valid) {
                const int r0 = mt * 16 + quad * 4;
#pragma unroll
                for (int rr = 0; rr < 4; ++rr) {
                    Cs[0][r0 + rr][lc] = c0[rr];
                    Cs[1][r0 + rr][lc] = c1[rr];
                }
            }
            __syncthreads();

            // gates + publish h1[i] into own contiguous block
            {
                const float xz = Cs[0][bb][jl]      + bxz;
                const float xr = Cs[0][bb][16 + jl] + bxr;
                const float xh = Cs[0][bb][32 + jl] + bxh;
                const float rz = Cs[1][bb][jl]      + bhz;
                const float rr = Cs[1][bb][16 + jl] + bhr;
                const float rh = Cs[1][bb][32 + jl] + bhh;
                const float z  = sigf(xz + rz);
                const float r  = sigf(xr + rr);
                const float hh = tanhfast(xh + r * rh);
                h1m = z * h1m + (1.f - z) * hh;
                const u64 v1 = gather4(f16b(h1m), jl);
                if ((jl & 3) == 0)
                    ST_A((u64*)(p1 + ((unsigned)(i & 3) * 16 + w) * PBLK + bb * 16 + jl), v1);
                asm volatile("s_waitcnt vmcnt(0)" ::: "memory");
            }
            __syncthreads();
            if (tid < 32) ST_A(&flags[(w * 32 + tid) * 16], (unsigned)(i + 1));
        }
    } else {
        // ================= L2 pipeline =================
        const int w    = blockIdx.x - NWG1;
        const int gcol = valid ? (gate * H_ + w * 16 + hidx) : 0;
        half8 fk2[8], frk2[8];
#pragma unroll
        for (int ks = 0; ks < 8; ++ks) {
            half8 f2, f3;
#pragma unroll
            for (int j = 0; j < 8; ++j) {
                const int k = ks * 32 + quad * 8 + j;
                const float v2 = k2 [k * G3_ + gcol];
                const float v3 = rk2[k * G3_ + gcol];
                f2[j] = valid ? (_Float16)v2 : (_Float16)0.f;
                f3[j] = valid ? (_Float16)v3 : (_Float16)0.f;
            }
            fk2[ks] = f2; frk2[ks] = f3;
        }
        const int gc = w * 16 + jl;
        const float bxz = b2[gc],       bxr = b2[H_ + gc],       bxh = b2[2 * H_ + gc];
        const float bhz = b2[G3_ + gc], bhr = b2[G3_ + H_ + gc], bhh = b2[G3_ + 2 * H_ + gc];
        float h2m = 0.f;

        // staging map: pk 0 = h1[t] (256 thr), pk 1 = h2[t-1] (256 thr);
        // 16 threads per source, 64 B each. PRIVATE poll line per (src, cons).
        const int pk  = tid >> 8;
        const int tt  = tid & 255;
        const int w2  = tt >> 4;
        const int l16 = tt & 15;
        const unsigned* fp = pk ? (flags + ((16 + w2) * 32 + 16 + w) * 16)
                                : (flags + (w2 * 32 + 16 + w) * 16);

        for (int t = 0; t < T_; ++t) {
            // poll own source, coalesced stage of its 1 KB block slice
            {
                const unsigned tgt = pk ? (unsigned)t : (unsigned)(t + 1);
                while (LD_A(fp) < tgt) __builtin_amdgcn_s_sleep(1);
                const u64* src = pk
                    ? (const u64*)(p2 + (((unsigned)(t + 1) & 1u) * 16 + w2) * PBLK)
                    : (const u64*)(p1 + (((unsigned)t & 3u) * 16 + w2) * PBLK);
                u64 q[8];
#pragma unroll
                for (int k = 0; k < 8; ++k) q[k] = LD_A(src + k * 16 + l16);
                _Float16 (*dst)[264] = pk ? h2s : h1s;
                const int c0f = w2 * 16 + (l16 & 3) * 4;
                const int b0  = l16 >> 2;          // bb for k=0
#pragma unroll
                for (int k = 0; k < 8; ++k)
                    *(u64*)(&dst[b0 + k * 4][c0f]) = q[k];
            }
            __syncthreads();
            if (tid < 16) ST_A(&prog[(w * 16 + tid) * 16], (unsigned)(t + 1));  // staged h1[t]

            f32x4 c2 = {0.f, 0.f, 0.f, 0.f};
            f32x4 c3 = c2;
#pragma unroll
            for (int ks = 0; ks < 8; ++ks) {
                half8 a1 = *(const half8*)(&h1s[m][ks * 32 + quad * 8]);
                half8 a2 = *(const half8*)(&h2s[m][ks * 32 + quad * 8]);
                c2 = __builtin_amdgcn_mfma_f32_16x16x32_f16(a1, fk2[ks],  c2, 0, 0, 0);
                c3 = __builtin_amdgcn_mfma_f32_16x16x32_f16(a2, frk2[ks], c3, 0, 0, 0);
            }
            if (valid) {
                const int r0 = mt * 16 + quad * 4;
#pragma unroll
                for (int rr = 0; rr < 4; ++rr) {
                    Cs[0][r0 + rr][lc] = c2[rr];
                    Cs[1][r0 + rr][lc] = c3[rr];
                }
            }
            __syncthreads();

            // gates + publish h2[t] into own contiguous block
            {
                const float xz = Cs[0][bb][jl]      + bxz;
                const float xr = Cs[0][bb][16 + jl] + bxr;
                const float xh = Cs[0][bb][32 + jl] + bxh;
                const float rz = Cs[1][bb][jl]      + bhz;
                const float rr = Cs[1][bb][16 + jl] + bhr;
                const float rh = Cs[1][bb][32 + jl] + bhh;
                const float z  = sigf(xz + rz);
                const float r  = sigf(xr + rr);
                const float hh = tanhfast(xh + r * rh);
                h2m = z * h2m + (1.f - z) * hh;
                const u64 v2 = gather4(f16b(h2m), jl);
                if ((jl & 3) == 0)
                    ST_A((u64*)(p2 + ((unsigned)(t & 1) * 16 + w) * PBLK + bb * 16 + jl), v2);
                asm volatile("s_waitcnt vmcnt(0)" ::: "memory");
            }
            __syncthreads();
            if (tid < 32) ST_A(&flags[((16 + w) * 32 + tid) * 16], (unsigned)(t + 1));
        }

        // ---- final dense: out[b][o] += sum_j h2[b][16w+j] * wd[16w+j][o]
        hs[bb][jl] = h2m;                // h2m = h2[T-1]
        __syncthreads();
        const int o  = tid & 63;
        const int bq = tid >> 6;         // 0..7
        for (int pass = 0; pass < 4; ++pass) {
            const int b = pass * 8 + bq;
            float acc = 0.f;
#pragma unroll
            for (int j = 0; j < 16; ++j) acc += hs[b][j] * wd[(w * 16 + j) * OUT_ + o];
            atomicAdd(&out[b * OUT_ + o], acc);
        }
    }
}

// ---------------------------------------------------------------------------
extern "C" void kernel_launch(void* const* d_in, const int* in_sizes, int n_in,
                              void* d_out, int out_size, void* d_ws, size_t ws_size,
                              hipStream_t stream) {
    const float* x     = (const float*)d_in[0];
    const float* gamma = (const float*)d_in[1];
    const float* beta  = (const float*)d_in[2];
    const float* k1    = (const float*)d_in[3];
    const float* rk1   = (const float*)d_in[4];
    const float* b1    = (const float*)d_in[5];
    const float* k2    = (const float*)d_in[6];
    const float* rk2   = (const float*)d_in[7];
    const float* b2    = (const float*)d_in[8];
    const float* wd    = (const float*)d_in[9];
    const float* bd    = (const float*)d_in[10];
    float* out = (float*)d_out;

    char* ws = (char*)d_ws;
    _Float16*     xn    = (_Float16*)ws;
    _Float16*     p1    = (_Float16*)(ws + S1_OFF);
    _Float16*     p2    = (_Float16*)(ws + S2_OFF);
    unsigned int* flags = (unsigned int*)(ws + FLAG_OFF);
    unsigned int* prog  = (unsigned int*)(ws + PROG_OFF);

    hipLaunchKernelGGL(init_kernel, dim3(16), dim3(256), 0, stream, out, bd, p1, flags);
    hipLaunchKernelGGL(ln_kernel, dim3(B_ * T_ / 16), dim3(256), 0, stream, x, gamma, beta, xn);

    void* args[] = {(void*)&xn, (void*)&k1, (void*)&rk1, (void*)&b1, (void*)&k2,
                    (void*)&rk2, (void*)&b2, (void*)&wd, (void*)&out,
                    (void*)&p1, (void*)&p2, (void*)&flags, (void*)&prog};
    hipLaunchCooperativeKernel((void*)gru_main, dim3(TOTAL_WG), dim3(WGT), args, 0, stream);
}